// Round 1
// baseline (373.253 us; speedup 1.0000x reference)
//
#include <hip/hip_runtime.h>

#define BB 32
#define CC 512
#define COO 512
#define HH 56
#define WW 56
#define EPSF 1e-5f
#define TH 28   // rows per K1 block

typedef unsigned long long u64;

// ---------------- workspace layout (bytes) ----------------
// s1     : u64[100352*8]  = 6,422,528   position-major packed sign bits after BN1
// wbits  : u64[512*8]     =    32,768
// bn1inv : float[512]
// bn1beta: float[512]
// bn2inv : float[512]
// bn2beta: float[512]
// dwsign : float[512*9]
#define OFF_S1      0
#define OFF_WBITS   6422528
#define OFF_BN1INV  6455296
#define OFF_BN1BETA 6457344
#define OFF_BN2INV  6459392
#define OFF_BN2BETA 6461440
#define OFF_DWSIGN  6463488

__global__ __launch_bounds__(256) void setup_kernel(
    const float* __restrict__ w_dw, const float* __restrict__ w_pw,
    const float* __restrict__ g1, const float* __restrict__ b1,
    const float* __restrict__ m1, const float* __restrict__ v1,
    const float* __restrict__ g2, const float* __restrict__ b2,
    const float* __restrict__ m2, const float* __restrict__ v2,
    u64* __restrict__ wbits, float* __restrict__ bn1inv, float* __restrict__ bn1beta,
    float* __restrict__ bn2inv, float* __restrict__ bn2beta, float* __restrict__ dwsign) {
    int t = blockIdx.x * 256 + threadIdx.x;   // 0..4095
    if (t < CC) {
        float i1 = g1[t] / sqrtf(v1[t] + EPSF);
        bn1inv[t]  = i1;
        bn1beta[t] = b1[t] - m1[t] * i1;
        float i2 = g2[t] / sqrtf(v2[t] + EPSF);
        bn2inv[t]  = i2;
        bn2beta[t] = b2[t] - m2[t] * i2;
        #pragma unroll
        for (int j = 0; j < 9; ++j) {
            float wv = w_dw[t * 9 + j];
            dwsign[t * 9 + j] = (wv > 0.f) ? 1.f : (wv < 0.f ? -1.f : 0.f);
        }
    }
    // pack pointwise weight signs: word wi of output o covers channels wi*64..wi*64+63
    {
        int o = t >> 3, wi = t & 7;
        const float* wp = w_pw + (size_t)o * CC + wi * 64;
        u64 wrd = 0;
        #pragma unroll 8
        for (int k = 0; k < 64; ++k)
            wrd |= (u64)(wp[k] >= 0.f) << k;
        wbits[t] = wrd;
    }
}

// K1: binarize(x) -> depthwise 3x3 (pad 1) -> BN1 -> sign -> bitpack over channels
// grid: (cw=8, htile=2, b=32), block 256
__global__ __launch_bounds__(256) void dw_kernel(
    const float* __restrict__ x, const float* __restrict__ dwsign,
    const float* __restrict__ bn1inv, const float* __restrict__ bn1beta,
    u64* __restrict__ s1) {
    __shared__ float tile[(TH + 2) * 58];
    const int cw  = blockIdx.x;
    const int h0  = blockIdx.y * TH;
    const int b   = blockIdx.z;
    const int tid = threadIdx.x;

    u64 acc[7];
    int lbase[7];
    #pragma unroll
    for (int k = 0; k < 7; ++k) {
        acc[k] = 0;
        int p = tid + k * 256;
        int row = p / WW, wc = p - row * WW;
        lbase[k] = row * 58 + wc;    // top-left tap (padded coords)
    }

    const float* xb = x + (size_t)b * CC * (HH * WW);

    for (int cl = 0; cl < 64; ++cl) {
        const int c = cw * 64 + cl;
        const float* xc = xb + (size_t)c * (HH * WW);
        __syncthreads();   // previous iter's reads done before overwrite
        for (int i = tid; i < (TH + 2) * 58; i += 256) {
            int r = i / 58, col = i - r * 58;
            int h = h0 - 1 + r, w = col - 1;
            float v = 0.f;
            if (h >= 0 && h < HH && w >= 0 && w < WW) {
                float xv = xc[h * WW + w];
                v = (xv > 0.f) ? 1.f : (xv < 0.f ? -1.f : 0.f);
            }
            tile[i] = v;
        }
        __syncthreads();

        const float* wsp = dwsign + c * 9;
        float ws0 = wsp[0], ws1 = wsp[1], ws2 = wsp[2];
        float ws3 = wsp[3], ws4 = wsp[4], ws5 = wsp[5];
        float ws6 = wsp[6], ws7 = wsp[7], ws8 = wsp[8];
        float i1 = bn1inv[c], be = bn1beta[c];

        #pragma unroll
        for (int k = 0; k < 7; ++k) {
            int p = tid + k * 256;
            if (p < TH * WW) {
                const float* t0 = tile + lbase[k];
                float s;
                s  = t0[0]   * ws0; s = fmaf(t0[1],   ws1, s); s = fmaf(t0[2],   ws2, s);
                s  = fmaf(t0[58],  ws3, s); s = fmaf(t0[59],  ws4, s); s = fmaf(t0[60],  ws5, s);
                s  = fmaf(t0[116], ws6, s); s = fmaf(t0[117], ws7, s); s = fmaf(t0[118], ws8, s);
                float y = fmaf(s, i1, be);
                acc[k] |= (u64)(y >= 0.f) << cl;
            }
        }
    }

    const size_t posbase = (size_t)b * (HH * WW) + (size_t)h0 * WW;
    #pragma unroll
    for (int k = 0; k < 7; ++k) {
        int p = tid + k * 256;
        if (p < TH * WW)
            s1[(posbase + p) * 8 + cw] = acc[k];
    }
}

// K2: 1x1 binary conv via XNOR-popcount + BN2
// grid: (posblk=392, ogrp=4), block 256; each thread = 1 spatial position
__global__ __launch_bounds__(256) void pw_kernel(
    const u64* __restrict__ s1, const u64* __restrict__ wbits,
    const float* __restrict__ bn2inv, const float* __restrict__ bn2beta,
    float* __restrict__ out) {
    __shared__ u64  wb[128 * 8];
    __shared__ float inv_s[128], beta_s[128];
    const int tid = threadIdx.x;
    const int o0  = blockIdx.y * 128;

    for (int i = tid; i < 1024; i += 256) wb[i] = wbits[(size_t)o0 * 8 + i];
    if (tid < 128) { inv_s[tid] = bn2inv[o0 + tid]; beta_s[tid] = bn2beta[o0 + tid]; }
    __syncthreads();

    const size_t p   = (size_t)blockIdx.x * 256 + tid;   // 0..100351
    const int    b   = (int)(p / (HH * WW));
    const int    idx = (int)(p - (size_t)b * (HH * WW));

    const u64* sp = s1 + p * 8;
    u64 r0 = sp[0], r1 = sp[1], r2 = sp[2], r3 = sp[3];
    u64 r4 = sp[4], r5 = sp[5], r6 = sp[6], r7 = sp[7];

    float* outp = out + ((size_t)b * COO) * (HH * WW) + idx;

    for (int ol = 0; ol < 128; ++ol) {
        const u64* w8 = wb + ol * 8;
        int d = __popcll(r0 ^ w8[0]) + __popcll(r1 ^ w8[1])
              + __popcll(r2 ^ w8[2]) + __popcll(r3 ^ w8[3])
              + __popcll(r4 ^ w8[4]) + __popcll(r5 ^ w8[5])
              + __popcll(r6 ^ w8[6]) + __popcll(r7 ^ w8[7]);
        float res = (float)(CC - 2 * d);
        outp[(size_t)(o0 + ol) * (HH * WW)] = fmaf(res, inv_s[ol], beta_s[ol]);
    }
}

extern "C" void kernel_launch(void* const* d_in, const int* in_sizes, int n_in,
                              void* d_out, int out_size, void* d_ws, size_t ws_size,
                              hipStream_t stream) {
    const float* x    = (const float*)d_in[0];
    const float* w_dw = (const float*)d_in[1];
    const float* w_pw = (const float*)d_in[2];
    const float* g1   = (const float*)d_in[3];
    const float* b1   = (const float*)d_in[4];
    const float* m1   = (const float*)d_in[5];
    const float* v1   = (const float*)d_in[6];
    const float* g2   = (const float*)d_in[7];
    const float* b2   = (const float*)d_in[8];
    const float* m2   = (const float*)d_in[9];
    const float* v2   = (const float*)d_in[10];

    char* ws = (char*)d_ws;
    u64*   s1      = (u64*)(ws + OFF_S1);
    u64*   wbits   = (u64*)(ws + OFF_WBITS);
    float* bn1inv  = (float*)(ws + OFF_BN1INV);
    float* bn1beta = (float*)(ws + OFF_BN1BETA);
    float* bn2inv  = (float*)(ws + OFF_BN2INV);
    float* bn2beta = (float*)(ws + OFF_BN2BETA);
    float* dwsign  = (float*)(ws + OFF_DWSIGN);

    setup_kernel<<<16, 256, 0, stream>>>(w_dw, w_pw, g1, b1, m1, v1, g2, b2, m2, v2,
                                         wbits, bn1inv, bn1beta, bn2inv, bn2beta, dwsign);

    dim3 g1d(8, 2, BB);
    dw_kernel<<<g1d, 256, 0, stream>>>(x, dwsign, bn1inv, bn1beta, s1);

    dim3 g2d(392, 4);
    pw_kernel<<<g2d, 256, 0, stream>>>(s1, wbits, bn2inv, bn2beta, (float*)d_out);
}

// Round 2
// 286.889 us; speedup vs baseline: 1.3010x; 1.3010x over previous
//
#include <hip/hip_runtime.h>

#define BB 32
#define CC 512
#define COO 512
#define HH 56
#define WW 56
#define HW 3136
#define NPOS 100352      // B*H*W
#define EPSF 1e-5f

typedef unsigned long long u64;

// ---------------- workspace layout (bytes) ----------------
// s1     : u64[8][100352] word-major  = 6,422,528
// wbits  : u64[512*8]     =    32,768
// bn1inv : float[512]
// bn1beta: float[512]
// bn2inv : float[512]
// bn2beta: float[512]
// dwsign : float[512*9]
#define OFF_S1      0
#define OFF_WBITS   6422528
#define OFF_BN1INV  6455296
#define OFF_BN1BETA 6457344
#define OFF_BN2INV  6459392
#define OFF_BN2BETA 6461440
#define OFF_DWSIGN  6463488

__device__ __forceinline__ float sgnf(float v) {
    return (v > 0.f) ? 1.f : ((v < 0.f) ? -1.f : 0.f);
}

__global__ __launch_bounds__(256) void setup_kernel(
    const float* __restrict__ w_dw, const float* __restrict__ w_pw,
    const float* __restrict__ g1, const float* __restrict__ b1,
    const float* __restrict__ m1, const float* __restrict__ v1,
    const float* __restrict__ g2, const float* __restrict__ b2,
    const float* __restrict__ m2, const float* __restrict__ v2,
    u64* __restrict__ wbits, float* __restrict__ bn1inv, float* __restrict__ bn1beta,
    float* __restrict__ bn2inv, float* __restrict__ bn2beta, float* __restrict__ dwsign) {
    int t = blockIdx.x * 256 + threadIdx.x;   // 0..4095
    if (t < CC) {
        float i1 = g1[t] / sqrtf(v1[t] + EPSF);
        bn1inv[t]  = i1;
        bn1beta[t] = b1[t] - m1[t] * i1;
        float i2 = g2[t] / sqrtf(v2[t] + EPSF);
        bn2inv[t]  = i2;
        bn2beta[t] = b2[t] - m2[t] * i2;
        #pragma unroll
        for (int j = 0; j < 9; ++j) {
            float wv = w_dw[t * 9 + j];
            dwsign[t * 9 + j] = sgnf(wv);
        }
    }
    // pack pointwise weight signs: word wi of output o covers channels wi*64..wi*64+63
    {
        int o = t >> 3, wi = t & 7;
        const float* wp = w_pw + (size_t)o * CC + wi * 64;
        u64 wrd = 0;
        #pragma unroll 8
        for (int k = 0; k < 64; ++k)
            wrd |= (u64)(wp[k] >= 0.f) << k;
        wbits[t] = wrd;
    }
}

// K1: binarize(x) -> depthwise 3x3 (pad 1) -> BN1 -> sign -> bitpack (word-major s1)
// flat grid: 784 blocks x 256 threads; thread = (b, cw, row, 4-col group)
__global__ __launch_bounds__(256) void dw_kernel(
    const float* __restrict__ x, const float* __restrict__ dwsign,
    const float* __restrict__ bn1inv, const float* __restrict__ bn1beta,
    u64* __restrict__ s1) {
    const int tau = blockIdx.x * 256 + threadIdx.x;   // 0..200703
    const int colgrp = tau % 14;
    int t2 = tau / 14;
    const int row = t2 % 56;
    t2 /= 56;                         // 0..255 = b*8+cw
    const int cw = t2 & 7;
    const int b  = t2 >> 3;
    const int col0 = colgrp * 4;

    const float* bp = x + ((size_t)b * CC + cw * 64) * HW;

    u64 acc[4] = {0, 0, 0, 0};

    for (int cl = 0; cl < 64; ++cl) {
        const float* cp = bp + (size_t)cl * HW;
        float sg[3][6];
        #pragma unroll
        for (int r = 0; r < 3; ++r) {
            int hr = row - 1 + r;
            if (hr >= 0 && hr < HH) {
                const float* rp = cp + hr * WW + col0;
                float4 v = *(const float4*)rp;
                sg[r][1] = sgnf(v.x); sg[r][2] = sgnf(v.y);
                sg[r][3] = sgnf(v.z); sg[r][4] = sgnf(v.w);
                sg[r][0] = (col0 > 0)      ? sgnf(rp[-1]) : 0.f;
                sg[r][5] = (col0 + 4 < WW) ? sgnf(rp[4])  : 0.f;
            } else {
                #pragma unroll
                for (int q = 0; q < 6; ++q) sg[r][q] = 0.f;
            }
        }
        const int c = cw * 64 + cl;
        const float* wsp = dwsign + c * 9;
        float w0 = wsp[0], w1 = wsp[1], w2 = wsp[2];
        float w3 = wsp[3], w4 = wsp[4], w5 = wsp[5];
        float w6 = wsp[6], w7 = wsp[7], w8 = wsp[8];
        const float i1 = bn1inv[c], be = bn1beta[c];
        #pragma unroll
        for (int j = 0; j < 4; ++j) {
            float s = sg[0][j] * w0;
            s = fmaf(sg[0][j+1], w1, s);
            s = fmaf(sg[0][j+2], w2, s);
            s = fmaf(sg[1][j],   w3, s);
            s = fmaf(sg[1][j+1], w4, s);
            s = fmaf(sg[1][j+2], w5, s);
            s = fmaf(sg[2][j],   w6, s);
            s = fmaf(sg[2][j+1], w7, s);
            s = fmaf(sg[2][j+2], w8, s);
            float y = fmaf(s, i1, be);
            acc[j] |= (u64)(y >= 0.f) << cl;
        }
    }

    // word-major: s1[cw][pos], pos = b*HW + row*W + col
    u64* sp = s1 + (size_t)cw * NPOS + (size_t)b * HW + row * WW + col0;
    *(ulonglong2*)(sp)     = make_ulonglong2(acc[0], acc[1]);
    *(ulonglong2*)(sp + 2) = make_ulonglong2(acc[2], acc[3]);
}

// K2: 1x1 binary conv via XNOR-popcount + BN2
// grid: (posblk=392, ogrp=4), block 256; each thread = 1 spatial position
__global__ __launch_bounds__(256) void pw_kernel(
    const u64* __restrict__ s1, const u64* __restrict__ wbits,
    const float* __restrict__ bn2inv, const float* __restrict__ bn2beta,
    float* __restrict__ out) {
    __shared__ u64  wb[128 * 8];
    __shared__ float inv_s[128], beta_s[128];
    const int tid = threadIdx.x;
    const int o0  = blockIdx.y * 128;

    for (int i = tid; i < 1024; i += 256) wb[i] = wbits[(size_t)o0 * 8 + i];
    if (tid < 128) { inv_s[tid] = bn2inv[o0 + tid]; beta_s[tid] = bn2beta[o0 + tid]; }
    __syncthreads();

    const size_t p   = (size_t)blockIdx.x * 256 + tid;   // 0..100351
    const int    b   = (int)(p / HW);
    const int    idx = (int)(p - (size_t)b * HW);

    u64 r0 = s1[0u * NPOS + p], r1 = s1[1u * NPOS + p];
    u64 r2 = s1[2u * NPOS + p], r3 = s1[3u * NPOS + p];
    u64 r4 = s1[4u * NPOS + p], r5 = s1[5u * NPOS + p];
    u64 r6 = s1[6u * NPOS + p], r7 = s1[7u * NPOS + p];

    float* outp = out + ((size_t)b * COO) * HW + idx;

    for (int ol = 0; ol < 128; ++ol) {
        const u64* w8 = wb + ol * 8;
        int d = __popcll(r0 ^ w8[0]) + __popcll(r1 ^ w8[1])
              + __popcll(r2 ^ w8[2]) + __popcll(r3 ^ w8[3])
              + __popcll(r4 ^ w8[4]) + __popcll(r5 ^ w8[5])
              + __popcll(r6 ^ w8[6]) + __popcll(r7 ^ w8[7]);
        float res = (float)(CC - 2 * d);
        outp[(size_t)(o0 + ol) * HW] = fmaf(res, inv_s[ol], beta_s[ol]);
    }
}

extern "C" void kernel_launch(void* const* d_in, const int* in_sizes, int n_in,
                              void* d_out, int out_size, void* d_ws, size_t ws_size,
                              hipStream_t stream) {
    const float* x    = (const float*)d_in[0];
    const float* w_dw = (const float*)d_in[1];
    const float* w_pw = (const float*)d_in[2];
    const float* g1   = (const float*)d_in[3];
    const float* b1   = (const float*)d_in[4];
    const float* m1   = (const float*)d_in[5];
    const float* v1   = (const float*)d_in[6];
    const float* g2   = (const float*)d_in[7];
    const float* b2   = (const float*)d_in[8];
    const float* m2   = (const float*)d_in[9];
    const float* v2   = (const float*)d_in[10];

    char* ws = (char*)d_ws;
    u64*   s1      = (u64*)(ws + OFF_S1);
    u64*   wbits   = (u64*)(ws + OFF_WBITS);
    float* bn1inv  = (float*)(ws + OFF_BN1INV);
    float* bn1beta = (float*)(ws + OFF_BN1BETA);
    float* bn2inv  = (float*)(ws + OFF_BN2INV);
    float* bn2beta = (float*)(ws + OFF_BN2BETA);
    float* dwsign  = (float*)(ws + OFF_DWSIGN);

    setup_kernel<<<16, 256, 0, stream>>>(w_dw, w_pw, g1, b1, m1, v1, g2, b2, m2, v2,
                                         wbits, bn1inv, bn1beta, bn2inv, bn2beta, dwsign);

    dw_kernel<<<784, 256, 0, stream>>>(x, dwsign, bn1inv, bn1beta, s1);

    dim3 g2d(392, 4);
    pw_kernel<<<g2d, 256, 0, stream>>>(s1, wbits, bn2inv, bn2beta, (float*)d_out);
}

// Round 3
// 221.158 us; speedup vs baseline: 1.6877x; 1.2972x over previous
//
#include <hip/hip_runtime.h>

#define BB 32
#define CC 512
#define COO 512
#define HH 56
#define WW 56
#define HW 3136
#define NPOS 100352      // B*H*W
#define EPSF 1e-5f

typedef unsigned long long u64;
typedef unsigned int u32;
typedef unsigned short u16;

// ---------------- workspace layout (bytes) ----------------
// s1     : u64[8][100352] word-major  = 6,422,528
// wbits  : u64[512*8]     =    32,768
// bn2inv : float[512]
// bn2beta: float[512]
// dwtab  : float4[512*3]  (w0..w8, inv1, beta1, 0) = 24,576
#define OFF_S1      0
#define OFF_WBITS   6422528
#define OFF_BN2INV  6455296
#define OFF_BN2BETA 6457344
#define OFF_DWTAB   6459392

__device__ __forceinline__ float sgnf(float v) {
    return (v > 0.f) ? 1.f : ((v < 0.f) ? -1.f : 0.f);
}
// ±1 sign for a.s.-nonzero values (2 VALU ops); padding handled separately
__device__ __forceinline__ float sgn1(float v) {
    return __uint_as_float((__float_as_uint(v) & 0x80000000u) | 0x3f800000u);
}

__global__ __launch_bounds__(256) void setup_kernel(
    const float* __restrict__ w_dw, const float* __restrict__ w_pw,
    const float* __restrict__ g1, const float* __restrict__ b1,
    const float* __restrict__ m1, const float* __restrict__ v1,
    const float* __restrict__ g2, const float* __restrict__ b2,
    const float* __restrict__ m2, const float* __restrict__ v2,
    u64* __restrict__ wbits, float* __restrict__ bn2inv, float* __restrict__ bn2beta,
    float4* __restrict__ dwtab) {
    int t = blockIdx.x * 256 + threadIdx.x;   // 0..4095
    if (t < CC) {
        float i1 = g1[t] / sqrtf(v1[t] + EPSF);
        float be = b1[t] - m1[t] * i1;
        float s[9];
        #pragma unroll
        for (int j = 0; j < 9; ++j) s[j] = sgnf(w_dw[t * 9 + j]);
        dwtab[t * 3 + 0] = make_float4(s[0], s[1], s[2], s[3]);
        dwtab[t * 3 + 1] = make_float4(s[4], s[5], s[6], s[7]);
        dwtab[t * 3 + 2] = make_float4(s[8], i1, be, 0.f);
        float i2 = g2[t] / sqrtf(v2[t] + EPSF);
        bn2inv[t]  = i2;
        bn2beta[t] = b2[t] - m2[t] * i2;
    }
    // pack pointwise weight signs: word wi of output o covers channels wi*64..wi*64+63
    {
        int o = t >> 3, wi = t & 7;
        const float* wp = w_pw + (size_t)o * CC + wi * 64;
        u64 wrd = 0;
        #pragma unroll 8
        for (int k = 0; k < 64; ++k)
            wrd |= (u64)(wp[k] >= 0.f) << k;
        wbits[t] = wrd;
    }
}

// K1: binarize(x) -> depthwise 3x3 (pad 1) -> BN1 -> sign -> bitpack (word-major s1)
// grid: (784, cg=4) x 256; thread = (b, cw, row, 4-col group), 16 channels each,
// stores one u16 slice of the u64 word per position.
__global__ __launch_bounds__(256) void dw_kernel(
    const float* __restrict__ x, const float4* __restrict__ dwtab,
    u64* __restrict__ s1) {
    const int tau = blockIdx.x * 256 + threadIdx.x;   // 0..200703
    const int cg  = blockIdx.y;                       // 0..3
    const int colgrp = tau % 14;
    int t2 = tau / 14;
    const int row = t2 % 56;
    t2 /= 56;                         // 0..255 = b*8+cw
    const int cw = t2 & 7;
    const int b  = t2 >> 3;
    const int col0 = colgrp * 4;
    const int c0 = cw * 64 + cg * 16;

    const float* bp = x + ((size_t)b * CC + c0) * HW;

    u32 acc[4] = {0, 0, 0, 0};

    for (int cl = 0; cl < 16; ++cl) {
        const float* cp = bp + (size_t)cl * HW;
        float sg[3][6];
        #pragma unroll
        for (int r = 0; r < 3; ++r) {
            int hr = row - 1 + r;
            if (hr >= 0 && hr < HH) {
                const float* rp = cp + hr * WW + col0;
                float4 v = *(const float4*)rp;
                sg[r][1] = sgn1(v.x); sg[r][2] = sgn1(v.y);
                sg[r][3] = sgn1(v.z); sg[r][4] = sgn1(v.w);
                sg[r][0] = (col0 > 0)      ? sgn1(rp[-1]) : 0.f;
                sg[r][5] = (col0 + 4 < WW) ? sgn1(rp[4])  : 0.f;
            } else {
                #pragma unroll
                for (int q = 0; q < 6; ++q) sg[r][q] = 0.f;
            }
        }
        const float4 q0 = dwtab[(c0 + cl) * 3 + 0];
        const float4 q1 = dwtab[(c0 + cl) * 3 + 1];
        const float4 q2 = dwtab[(c0 + cl) * 3 + 2];
        #pragma unroll
        for (int j = 0; j < 4; ++j) {
            float s = sg[0][j] * q0.x;
            s = fmaf(sg[0][j+1], q0.y, s);
            s = fmaf(sg[0][j+2], q0.z, s);
            s = fmaf(sg[1][j],   q0.w, s);
            s = fmaf(sg[1][j+1], q1.x, s);
            s = fmaf(sg[1][j+2], q1.y, s);
            s = fmaf(sg[2][j],   q1.z, s);
            s = fmaf(sg[2][j+1], q1.w, s);
            s = fmaf(sg[2][j+2], q2.x, s);
            float y = fmaf(s, q2.y, q2.z);
            acc[j] |= (u32)(y >= 0.f) << cl;
        }
    }

    // word-major: s1[cw][pos]; this block writes halfword cg of each u64
    const size_t w = (size_t)cw * NPOS + (size_t)b * HW + row * WW + col0;
    u16* sp = (u16*)s1;
    #pragma unroll
    for (int j = 0; j < 4; ++j)
        sp[(w + j) * 4 + cg] = (u16)acc[j];
}

// K2: 1x1 binary conv via XNOR-popcount + BN2
// grid: (posblk=392, ogrp=4), block 256; each thread = 1 spatial position
__global__ __launch_bounds__(256) void pw_kernel(
    const u64* __restrict__ s1, const u64* __restrict__ wbits,
    const float* __restrict__ bn2inv, const float* __restrict__ bn2beta,
    float* __restrict__ out) {
    __shared__ u64  wb[128 * 8];
    __shared__ float inv_s[128], beta_s[128];
    const int tid = threadIdx.x;
    const int o0  = blockIdx.y * 128;

    for (int i = tid; i < 1024; i += 256) wb[i] = wbits[(size_t)o0 * 8 + i];
    if (tid < 128) { inv_s[tid] = bn2inv[o0 + tid]; beta_s[tid] = bn2beta[o0 + tid]; }
    __syncthreads();

    const size_t p   = (size_t)blockIdx.x * 256 + tid;   // 0..100351
    const int    b   = (int)(p / HW);
    const int    idx = (int)(p - (size_t)b * HW);

    u64 r0 = s1[0u * NPOS + p], r1 = s1[1u * NPOS + p];
    u64 r2 = s1[2u * NPOS + p], r3 = s1[3u * NPOS + p];
    u64 r4 = s1[4u * NPOS + p], r5 = s1[5u * NPOS + p];
    u64 r6 = s1[6u * NPOS + p], r7 = s1[7u * NPOS + p];

    float* outp = out + ((size_t)b * COO) * HW + idx;

    for (int ol = 0; ol < 128; ++ol) {
        const u64* w8 = wb + ol * 8;
        int d = __popcll(r0 ^ w8[0]) + __popcll(r1 ^ w8[1])
              + __popcll(r2 ^ w8[2]) + __popcll(r3 ^ w8[3])
              + __popcll(r4 ^ w8[4]) + __popcll(r5 ^ w8[5])
              + __popcll(r6 ^ w8[6]) + __popcll(r7 ^ w8[7]);
        float res = (float)(CC - 2 * d);
        outp[(size_t)(o0 + ol) * HW] = fmaf(res, inv_s[ol], beta_s[ol]);
    }
}

extern "C" void kernel_launch(void* const* d_in, const int* in_sizes, int n_in,
                              void* d_out, int out_size, void* d_ws, size_t ws_size,
                              hipStream_t stream) {
    const float* x    = (const float*)d_in[0];
    const float* w_dw = (const float*)d_in[1];
    const float* w_pw = (const float*)d_in[2];
    const float* g1   = (const float*)d_in[3];
    const float* b1   = (const float*)d_in[4];
    const float* m1   = (const float*)d_in[5];
    const float* v1   = (const float*)d_in[6];
    const float* g2   = (const float*)d_in[7];
    const float* b2   = (const float*)d_in[8];
    const float* m2   = (const float*)d_in[9];
    const float* v2   = (const float*)d_in[10];

    char* ws = (char*)d_ws;
    u64*   s1      = (u64*)(ws + OFF_S1);
    u64*   wbits   = (u64*)(ws + OFF_WBITS);
    float* bn2inv  = (float*)(ws + OFF_BN2INV);
    float* bn2beta = (float*)(ws + OFF_BN2BETA);
    float4* dwtab  = (float4*)(ws + OFF_DWTAB);

    setup_kernel<<<16, 256, 0, stream>>>(w_dw, w_pw, g1, b1, m1, v1, g2, b2, m2, v2,
                                         wbits, bn2inv, bn2beta, dwtab);

    dim3 g1d(784, 4);
    dw_kernel<<<g1d, 256, 0, stream>>>(x, dwtab, s1);

    dim3 g2d(392, 4);
    pw_kernel<<<g2d, 256, 0, stream>>>(s1, wbits, bn2inv, bn2beta, (float*)d_out);
}

// Round 5
// 154.218 us; speedup vs baseline: 2.4203x; 1.4341x over previous
//
#include <hip/hip_runtime.h>

#define BB 32
#define CC 512
#define COO 512
#define HH 56
#define WW 56
#define HW 3136
#define NPOS 100352      // B*H*W
#define EPSF 1e-5f

typedef unsigned long long u64;
typedef unsigned int u32;
typedef unsigned short u16;

// ---------------- workspace layout (bytes) ----------------  total 6,460,928
// s1     : u64[8][NPOS]  = 6,422,528   stage-1 sign bits (word-major)
// wbits  : u64[512*8]    = 32,768      pointwise weight sign bits
// wn     : u64[9*8]      = 576         ~sign(w_dw) per tap per cw
// NT     : u64[3*8*5]    = 960         per-(Nv cat, cw): 4 planes of ~T* + flip
// bn2inv/bn2beta : float[512] each
#define OFF_S1      0
#define OFF_WBITS   6422528
#define OFF_WN      6455296
#define OFF_NT      6455872
#define OFF_BN2INV  6456832
#define OFF_BN2BETA 6458880

__global__ __launch_bounds__(256) void setup_kernel(
    const float* __restrict__ w_dw, const float* __restrict__ w_pw,
    const float* __restrict__ g1, const float* __restrict__ b1,
    const float* __restrict__ m1, const float* __restrict__ v1,
    const float* __restrict__ g2, const float* __restrict__ b2,
    const float* __restrict__ m2, const float* __restrict__ v2,
    u64* __restrict__ wbits, u64* __restrict__ wn, u64* __restrict__ NT,
    float* __restrict__ bn2inv, float* __restrict__ bn2beta) {
    const int t = blockIdx.x * 256 + threadIdx.x;   // 0..4095

    // pointwise weight sign bits (all 4096 threads)
    {
        int o = t >> 3, wi = t & 7;
        const float* wp = w_pw + (size_t)o * CC + wi * 64;
        u64 wrd = 0;
        #pragma unroll 8
        for (int k = 0; k < 64; ++k)
            wrd |= (u64)(wp[k] >= 0.f) << k;
        wbits[t] = wrd;
    }

    if (t < CC) {                       // BN2 affine
        float i2 = g2[t] / sqrtf(v2[t] + EPSF);
        bn2inv[t]  = i2;
        bn2beta[t] = b2[t] - m2[t] * i2;
    } else if (t >= 512 && t < 584) {   // depthwise weight ~sign words
        int q = t - 512, cw = q & 7, tap = q >> 3;   // tap = kh*3+kw
        u64 wv = 0;
        for (int cl = 0; cl < 64; ++cl)
            wv |= (u64)(w_dw[(size_t)(cw * 64 + cl) * 9 + tap] < 0.f) << cl;
        wn[tap * 8 + cw] = wv;
    } else if (t >= 1024 && t < 1048) { // BN1 threshold bitplanes
        int q = t - 1024, cat = q / 8, cw = q % 8;
        const int Nv = (cat == 0) ? 9 : ((cat == 1) ? 6 : 4);
        u64 p0 = 0, p1 = 0, p2 = 0, p3 = 0, F = 0;
        for (int cl = 0; cl < 64; ++cl) {
            int c = cw * 64 + cl;
            float i1 = g1[c] / sqrtf(v1[c] + EPSF);
            float be = b1[c] - m1[c] * i1;
            int T, f;
            if (i1 > 0.f) {
                double h = ((double)Nv - (double)be / (double)i1) * 0.5;
                f = 0;
                if (!(h > 0.0)) T = 0;
                else if (h > 15.0) T = 15;
                else T = (int)ceil(h);
            } else if (i1 < 0.f) {
                double h = ((double)Nv - (double)be / (double)i1) * 0.5;
                f = 1;
                if (h < 0.0) T = 0;
                else if (h >= 15.0) T = 15;
                else { T = (int)floor(h) + 1; if (T > 15) T = 15; }
            } else {
                f = 0;
                T = (be >= 0.f) ? 0 : 15;   // always true / never true (E<=9<15)
            }
            unsigned nt = (~(unsigned)T) & 0xFu;
            p0 |= (u64)(nt & 1) << cl;
            p1 |= (u64)((nt >> 1) & 1) << cl;
            p2 |= (u64)((nt >> 2) & 1) << cl;
            p3 |= (u64)((nt >> 3) & 1) << cl;
            F  |= (u64)f << cl;
        }
        u64* d = NT + (size_t)(cat * 8 + cw) * 5;
        d[0] = p0; d[1] = p1; d[2] = p2; d[3] = p3; d[4] = F;
    }
}

__device__ __forceinline__ void fa(u64 a, u64 b, u64 c, u64& s, u64& cy) {
    u64 ab = a ^ b;
    s  = ab ^ c;
    cy = (ab & c) | (a & b);
}

// Fused: binarize(x) -> LDS bitpack -> depthwise 3x3 + BN1 + sign (bit-domain) -> s1
// grid (strip=4, cw=8, b=32) x 256; strip covers 14 output rows (+2 halo rows in LDS)
__global__ __launch_bounds__(256) void dwfused_kernel(
    const float* __restrict__ x, const u64* __restrict__ wn,
    const u64* __restrict__ NT, u64* __restrict__ s1) {
    __shared__ u64 xb[16 * 56];          // rows r0-1 .. r0+14, 7168 B
    const int strip = blockIdx.x;
    const int cw    = blockIdx.y;
    const int b     = blockIdx.z;
    const int tid   = threadIdx.x;
    const int r0    = strip * 14;

    const float* xc = x + ((size_t)b * CC + cw * 64) * HW;
    u16* xb16 = (u16*)xb;

    // ---- pack phase: 896 tasks = 16 lds-rows x 14 colgroups x 4 channel-slices
    for (int tau = tid; tau < 896; tau += 256) {
        const int lrow   = tau / 56;
        const int rest   = tau - lrow * 56;
        const int colgrp = rest >> 2, cg = rest & 3;
        const int h      = r0 - 1 + lrow;
        const int col0   = colgrp * 4;
        u16 o0 = 0, o1 = 0, o2 = 0, o3 = 0;
        if (h >= 0 && h < HH) {
            const float* bp = xc + (size_t)(cg * 16) * HW + h * WW + col0;
            u32 a0 = 0, a1 = 0, a2 = 0, a3 = 0;
            #pragma unroll
            for (int cl = 0; cl < 16; ++cl) {
                float4 v = *(const float4*)(bp + (size_t)cl * HW);
                a0 |= (__float_as_uint(v.x) >> 31) << cl;
                a1 |= (__float_as_uint(v.y) >> 31) << cl;
                a2 |= (__float_as_uint(v.z) >> 31) << cl;
                a3 |= (__float_as_uint(v.w) >> 31) << cl;
            }
            o0 = (u16)(~a0); o1 = (u16)(~a1); o2 = (u16)(~a2); o3 = (u16)(~a3);
        }
        const int wbase = lrow * 56 + col0;
        xb16[(wbase + 0) * 4 + cg] = o0;
        xb16[(wbase + 1) * 4 + cg] = o1;
        xb16[(wbase + 2) * 4 + cg] = o2;
        xb16[(wbase + 3) * 4 + cg] = o3;
    }
    __syncthreads();

    // ---- compute phase: 196 threads x 4 output words
    if (tid >= 196) return;
    const int q      = tid / 14;          // row within strip
    const int colgrp = tid - q * 14;
    const int col0   = colgrp * 4;
    const int r      = r0 + q;            // global row
    const int lrow   = q + 1;

    const int c_m1 = (col0 == 0)  ? 0  : col0 - 1;
    const int c_p4 = (col0 == 52) ? 55 : col0 + 4;

    const u64* rowT = xb + (lrow - 1) * 56;
    const u64* rowM = xb + lrow * 56;
    const u64* rowB = xb + (lrow + 1) * 56;

    u64 rT[6], rM[6], rB[6];
    rT[0] = rowT[c_m1]; rT[1] = rowT[col0];   rT[2] = rowT[col0+1];
    rT[3] = rowT[col0+2]; rT[4] = rowT[col0+3]; rT[5] = rowT[c_p4];
    rM[0] = rowM[c_m1]; rM[1] = rowM[col0];   rM[2] = rowM[col0+1];
    rM[3] = rowM[col0+2]; rM[4] = rowM[col0+3]; rM[5] = rowM[c_p4];
    rB[0] = rowB[c_m1]; rB[1] = rowB[col0];   rB[2] = rowB[col0+1];
    rB[3] = rowB[col0+2]; rB[4] = rowB[col0+3]; rB[5] = rowB[c_p4];

    const u64 w00 = wn[0*8+cw], w01 = wn[1*8+cw], w02 = wn[2*8+cw];
    const u64 w10 = wn[3*8+cw], w11 = wn[4*8+cw], w12 = wn[5*8+cw];
    const u64 w20 = wn[6*8+cw], w21 = wn[7*8+cw], w22 = wn[8*8+cw];

    const u64 mt = (r > 0)    ? ~0ull : 0ull;
    const u64 mb = (r < 55)   ? ~0ull : 0ull;
    const u64 mL = (col0 > 0) ? ~0ull : 0ull;
    const u64 mR = (col0 < 52)? ~0ull : 0ull;

    const bool rowe = (r == 0) || (r == 55);
    const u64* NTc = NT + (size_t)cw * 5;   // cat stride = 40 u64
    u64 A0 = rowe ? NTc[40+0] : NTc[0];
    u64 A1 = rowe ? NTc[40+1] : NTc[1];
    u64 A2 = rowe ? NTc[40+2] : NTc[2];
    u64 A3 = rowe ? NTc[40+3] : NTc[3];
    u64 A4 = rowe ? NTc[40+4] : NTc[4];
    u64 B0 = rowe ? NTc[80+0] : NTc[40+0];
    u64 B1 = rowe ? NTc[80+1] : NTc[40+1];
    u64 B2 = rowe ? NTc[80+2] : NTc[40+2];
    u64 B3 = rowe ? NTc[80+3] : NTc[40+3];
    u64 B4 = rowe ? NTc[80+4] : NTc[40+4];

    u64 out[4];
    #pragma unroll
    for (int j = 0; j < 4; ++j) {
        u64 e0 = (rT[j]   ^ w00) & mt;
        u64 e1 = (rT[j+1] ^ w01) & mt;
        u64 e2 = (rT[j+2] ^ w02) & mt;
        u64 e3 = (rM[j]   ^ w10);
        u64 e4 = (rM[j+1] ^ w11);
        u64 e5 = (rM[j+2] ^ w12);
        u64 e6 = (rB[j]   ^ w20) & mb;
        u64 e7 = (rB[j+1] ^ w21) & mb;
        u64 e8 = (rB[j+2] ^ w22) & mb;
        if (j == 0) { e0 &= mL; e3 &= mL; e6 &= mL; }
        if (j == 3) { e2 &= mR; e5 &= mR; e8 &= mR; }

        u64 sa, ca, sb, cb, sc, cc, E0, cd, se, ce;
        fa(e0, e1, e2, sa, ca);
        fa(e3, e4, e5, sb, cb);
        fa(e6, e7, e8, sc, cc);
        fa(sa, sb, sc, E0, cd);
        fa(ca, cb, cc, se, ce);
        u64 E1 = se ^ cd, cf = se & cd;
        u64 E2 = ce ^ cf, E3 = ce & cf;

        u64 n0, n1, n2, n3, Fv;
        if (j == 0) {
            u64 m = (col0 == 0) ? ~0ull : 0ull;
            n0 = (B0 & m) | (A0 & ~m); n1 = (B1 & m) | (A1 & ~m);
            n2 = (B2 & m) | (A2 & ~m); n3 = (B3 & m) | (A3 & ~m);
            Fv = (B4 & m) | (A4 & ~m);
        } else if (j == 3) {
            u64 m = (col0 == 52) ? ~0ull : 0ull;
            n0 = (B0 & m) | (A0 & ~m); n1 = (B1 & m) | (A1 & ~m);
            n2 = (B2 & m) | (A2 & ~m); n3 = (B3 & m) | (A3 & ~m);
            Fv = (B4 & m) | (A4 & ~m);
        } else {
            n0 = A0; n1 = A1; n2 = A2; n3 = A3; Fv = A4;
        }

        // carry-out of E + ~T* + 1  ->  (E >= T*)
        u64 c = E0 | n0;
        c = (E1 & n1) | (c & (E1 | n1));
        c = (E2 & n2) | (c & (E2 | n2));
        c = (E3 & n3) | (c & (E3 | n3));
        out[j] = c ^ Fv;
    }

    u64* sp = s1 + (size_t)cw * NPOS + (size_t)b * HW + r * WW + col0;
    *(ulonglong2*)(sp)     = make_ulonglong2(out[0], out[1]);
    *(ulonglong2*)(sp + 2) = make_ulonglong2(out[2], out[3]);
}

// K2: 1x1 binary conv via XNOR-popcount + BN2
__global__ __launch_bounds__(256) void pw_kernel(
    const u64* __restrict__ s1, const u64* __restrict__ wbits,
    const float* __restrict__ bn2inv, const float* __restrict__ bn2beta,
    float* __restrict__ out) {
    __shared__ u64  wb[128 * 8];
    __shared__ float inv_s[128], beta_s[128];
    const int tid = threadIdx.x;
    const int o0  = blockIdx.y * 128;

    for (int i = tid; i < 1024; i += 256) wb[i] = wbits[(size_t)o0 * 8 + i];
    if (tid < 128) { inv_s[tid] = bn2inv[o0 + tid]; beta_s[tid] = bn2beta[o0 + tid]; }
    __syncthreads();

    const size_t p   = (size_t)blockIdx.x * 256 + tid;
    const int    b   = (int)(p / HW);
    const int    idx = (int)(p - (size_t)b * HW);

    u64 r0 = s1[0u * NPOS + p], r1 = s1[1u * NPOS + p];
    u64 r2 = s1[2u * NPOS + p], r3 = s1[3u * NPOS + p];
    u64 r4 = s1[4u * NPOS + p], r5 = s1[5u * NPOS + p];
    u64 r6 = s1[6u * NPOS + p], r7 = s1[7u * NPOS + p];

    float* outp = out + ((size_t)b * COO) * HW + idx;

    for (int ol = 0; ol < 128; ++ol) {
        const u64* w8 = wb + ol * 8;
        int d = __popcll(r0 ^ w8[0]) + __popcll(r1 ^ w8[1])
              + __popcll(r2 ^ w8[2]) + __popcll(r3 ^ w8[3])
              + __popcll(r4 ^ w8[4]) + __popcll(r5 ^ w8[5])
              + __popcll(r6 ^ w8[6]) + __popcll(r7 ^ w8[7]);
        float res = (float)(CC - 2 * d);
        outp[(size_t)(o0 + ol) * HW] = fmaf(res, inv_s[ol], beta_s[ol]);
    }
}

extern "C" void kernel_launch(void* const* d_in, const int* in_sizes, int n_in,
                              void* d_out, int out_size, void* d_ws, size_t ws_size,
                              hipStream_t stream) {
    const float* x    = (const float*)d_in[0];
    const float* w_dw = (const float*)d_in[1];
    const float* w_pw = (const float*)d_in[2];
    const float* g1   = (const float*)d_in[3];
    const float* b1   = (const float*)d_in[4];
    const float* m1   = (const float*)d_in[5];
    const float* v1   = (const float*)d_in[6];
    const float* g2   = (const float*)d_in[7];
    const float* b2   = (const float*)d_in[8];
    const float* m2   = (const float*)d_in[9];
    const float* v2   = (const float*)d_in[10];

    char* ws = (char*)d_ws;
    u64*   s1      = (u64*)(ws + OFF_S1);
    u64*   wbits   = (u64*)(ws + OFF_WBITS);
    u64*   wn      = (u64*)(ws + OFF_WN);
    u64*   NTarr   = (u64*)(ws + OFF_NT);
    float* bn2inv  = (float*)(ws + OFF_BN2INV);
    float* bn2beta = (float*)(ws + OFF_BN2BETA);

    setup_kernel<<<16, 256, 0, stream>>>(w_dw, w_pw, g1, b1, m1, v1, g2, b2, m2, v2,
                                         wbits, wn, NTarr, bn2inv, bn2beta);

    dim3 gf(4, 8, BB);
    dwfused_kernel<<<gf, 256, 0, stream>>>(x, wn, NTarr, s1);

    dim3 g2d(392, 4);
    pw_kernel<<<g2d, 256, 0, stream>>>(s1, wbits, bn2inv, bn2beta, (float*)d_out);
}